// Round 7
// baseline (569.480 us; speedup 1.0000x reference)
//
#include <hip/hip_runtime.h>

typedef _Float16 f16x8 __attribute__((ext_vector_type(8)));
typedef float    f32x4 __attribute__((ext_vector_type(4)));
typedef unsigned short u16;

#define VOC   128000
#define TOPIC 512
#define EMB   1024
#define BATCH 1024
#define ROWB  128   // LDS row = 64 f16 = 128 B

__device__ __forceinline__ int swz(int row, int kbyte) {
    return row * ROWB + (kbyte ^ ((row & 7) << 4));
}
// General bijective XCD-chunked swizzle (m204), any nwg.
__device__ __forceinline__ int xcd_swz(int bid, int nwg) {
    int x = bid & 7, o = bid >> 3, q = nwg >> 3, r = nwg & 7;
    return (x < r ? x * (q + 1) : r * (q + 1) + (x - r) * q) + o;
}
union H2U { _Float16 h; u16 u; };

#define SBAR() asm volatile("s_barrier" ::: "memory")
#define WVM0() asm volatile("s_waitcnt vmcnt(0)" ::: "memory")
#define WLG0() asm volatile("s_waitcnt lgkmcnt(0)" ::: "memory")

#define GLDS(SRC, DST) __builtin_amdgcn_global_load_lds( \
    (const __attribute__((address_space(1))) unsigned int*)(SRC), \
    (__attribute__((address_space(3))) unsigned int*)(DST), 16, 0, 0)

// Shared phase macros (bufA/bufB, af/bf/acc, wr/wc/lr/lk must be in scope)
#define RD_A(MH, KS) { _Pragma("unroll") \
    for (int m = 0; m < 4; ++m) \
        af[m] = *(const f16x8*)(bufA + wr * 16384 + \
            swz((MH) * 64 + m * 16 + lr, (KS) * 64 + lk * 16)); }
#define RD_B(KS) { _Pragma("unroll") \
    for (int n = 0; n < 4; ++n) \
        bf[n] = *(const f16x8*)(bufB + (wc >> 1) * 16384 + \
            swz((wc & 1) * 64 + n * 16 + lr, (KS) * 64 + lk * 16)); }
#define MFMA16(MH) { \
    __builtin_amdgcn_s_setprio(1); \
    _Pragma("unroll") for (int m = 0; m < 4; ++m) \
    _Pragma("unroll") for (int n = 0; n < 4; ++n) \
        acc[(MH) * 4 + m][n] = __builtin_amdgcn_mfma_f32_16x16x32_f16( \
            af[m], bf[n], acc[(MH) * 4 + m][n], 0, 0, 0); \
    __builtin_amdgcn_s_setprio(0); }

// ---------------------------------------------------------------------------
// K0: betat f32 -> f16 (into the ws MB that xst later overwrites with xsT)
// ---------------------------------------------------------------------------
__global__ void cvt_betat_kernel(const float* __restrict__ betat, u16* __restrict__ bt16) {
    const size_t g = (size_t)blockIdx.x * 256 + threadIdx.x;
    const float4* src = reinterpret_cast<const float4*>(betat) + g * 2;
    float4 a = src[0], b = src[1];
    f16x8 h;
    h[0]=(_Float16)a.x; h[1]=(_Float16)a.y; h[2]=(_Float16)a.z; h[3]=(_Float16)a.w;
    h[4]=(_Float16)b.x; h[5]=(_Float16)b.y; h[6]=(_Float16)b.z; h[7]=(_Float16)b.w;
    *(reinterpret_cast<f16x8*>(bt16) + g) = h;
}

// ---------------------------------------------------------------------------
// K1: W = beta0 [V,E] @ bt16^T; E = f16(exp(W)) -> first 1024 B of out rows;
//     col sums. 256x256 tile, BK=64, 8 waves (2x4), 4-phase/K-tile schedule.
//     A: f32 reg-load (phases a,b) + cvt/ds_write (phases c,d). B: gload_lds.
// ---------------------------------------------------------------------------
__global__ __launch_bounds__(512, 2) void gemm1_kernel(
    const float* __restrict__ beta0, const u16* __restrict__ bt16,
    u16* __restrict__ Eg, float* __restrict__ sg)
{
    __shared__ char lds[131072];   // per dbuf: A[h0|h1] 32K, B[h0|h1] 32K

    const int tid  = threadIdx.x;
    const int lane = tid & 63;
    const int wid  = tid >> 6;
    const int wr = wid >> 2, wc = wid & 3;
    const int lr = lane & 15, lk = lane >> 4;
    const int srow8  = lane >> 3;
    const int schunk = ((lane & 7) ^ srow8) * 8;

    const int bid   = xcd_swz(blockIdx.x, gridDim.x);
    const int tile  = bid >> 1;
    const int chunk = bid & 1;
    const int v0 = tile * 256, t0 = chunk * 256;

    const int a_row = tid >> 1, a_kh = tid & 1;     // A-stage: 1 row-half per thread
    const float* aRowP = beta0 + (size_t)(v0 + a_row) * EMB + a_kh * 32;

    f32x4 acc[8][4] = {};
    f16x8 af[4], bf[4];
    float4 rA[8];

    auto loadA4 = [&](int kt, int j0) {
        const float4* g = reinterpret_cast<const float4*>(aRowP + kt * 64);
        #pragma unroll
        for (int j = 0; j < 4; ++j) rA[j0 + j] = g[j0 + j];
    };
    auto cvtA = [&](int kt1, int j0) {   // rA[j0..j0+3] -> A buf of tile kt1
        char* dA = lds + (kt1 & 1) * 65536 + (a_row >> 7) * 16384;
        const int rl = a_row & 127;
        #pragma unroll
        for (int jj = 0; jj < 2; ++jj) {
            float4 xx = rA[j0 + jj * 2], yy = rA[j0 + jj * 2 + 1];
            f16x8 h;
            h[0]=(_Float16)xx.x; h[1]=(_Float16)xx.y; h[2]=(_Float16)xx.z; h[3]=(_Float16)xx.w;
            h[4]=(_Float16)yy.x; h[5]=(_Float16)yy.y; h[6]=(_Float16)yy.z; h[7]=(_Float16)yy.w;
            *(f16x8*)(dA + swz(rl, (a_kh * 4 + (j0 >> 1) + jj) * 16)) = h;
        }
    };
    auto stageB = [&](int kt, int h) {
        char* dstb = lds + (kt & 1) * 65536 + 32768 + h * 16384;
        #pragma unroll
        for (int q = 0; q < 2; ++q) {
            const u16* s_ = bt16 + (size_t)(t0 + h * 128 + wid * 16 + q * 8 + srow8) * EMB
                          + kt * 64 + schunk;
            GLDS(s_, dstb + (wid * 16 + q * 8) * ROWB);
        }
    };

    // prologue: tile 0 fully staged
    loadA4(0, 0); loadA4(0, 4);
    stageB(0, 0); stageB(0, 1);
    cvtA(0, 0); cvtA(0, 4);
    WLG0();

    for (int t = 0; t < 16; ++t) {
        char* bufA = lds + (t & 1) * 65536;
        char* bufB = bufA + 32768;
        const bool st = (t + 1) < 16;

        WVM0();   // tile t's B (issued during t-1) landed; nothing newer in flight
        SBAR();   // cross-wave: tile t fully in LDS
        RD_A(0, 0); RD_B(0);
        if (st) { loadA4(t + 1, 0); stageB(t + 1, 0); }
        MFMA16(0);
        SBAR();
        RD_A(1, 0);
        if (st) { loadA4(t + 1, 4); stageB(t + 1, 1); }
        MFMA16(1);
        SBAR();
        RD_A(0, 1); RD_B(1);
        if (st) cvtA(t + 1, 0);
        MFMA16(0);
        SBAR();
        RD_A(1, 1);
        if (st) cvtA(t + 1, 4);
        MFMA16(1);
        WLG0();   // own ds_writes drained before next tile-top barrier
    }

    // Epilogue: 4 chunks of 64 rows; exp -> LDS repack -> E write + col sums
    __syncthreads();
    u16* ldsE = reinterpret_cast<u16*>(lds);   // 64 x 264 u16
    float csum = 0.f;
    #pragma unroll
    for (int c = 0; c < 4; ++c) {
        if (wr == (c >> 1)) {
            const int mb = (c & 1) * 4;
            #pragma unroll
            for (int m = 0; m < 4; ++m)
              #pragma unroll
              for (int n = 0; n < 4; ++n)
                #pragma unroll
                for (int r = 0; r < 4; ++r) {
                    const int row = m * 16 + lk * 4 + r;        // 0..63
                    const int col = wc * 64 + n * 16 + lr;      // 0..255
                    H2U cv; cv.h = (_Float16)__expf(acc[mb + m][n][r]);
                    ldsE[row * 264 + col] = cv.u;
                }
        }
        __syncthreads();
        {
            const int row8 = tid >> 3, seg = tid & 7;
            const int4* sp = reinterpret_cast<const int4*>(&ldsE[row8 * 264 + seg * 32]);
            u16* dst = Eg + (size_t)(v0 + c * 64 + row8) * 2048 + t0 + seg * 32;
            int4 a0 = sp[0], a1 = sp[1], a2 = sp[2], a3 = sp[3];
            int4* dp = reinterpret_cast<int4*>(dst);
            dp[0] = a0; dp[1] = a1; dp[2] = a2; dp[3] = a3;
        }
        if (tid < 256) {
            float s = 0.f;
            for (int r = 0; r < 64; ++r) { H2U cv; cv.u = ldsE[r * 264 + tid]; s += (float)cv.h; }
            csum += s;
        }
        __syncthreads();
    }
    if (tid < 256) atomicAdd(sg + t0 + tid, csum);
}

// ---------------------------------------------------------------------------
// K2: xsT[b][t] = f16( x[t][b] * 65536 / s[t] )
// ---------------------------------------------------------------------------
__global__ void xst_kernel(const float* __restrict__ x, const float* __restrict__ s,
                           u16* __restrict__ xsT)
{
    __shared__ float tile[32][33];
    const int b0 = blockIdx.x * 32, t0 = blockIdx.y * 32;
    const int tx = threadIdx.x, ty = threadIdx.y;
    tile[ty][tx] = x[(size_t)(t0 + ty) * BATCH + b0 + tx];
    __syncthreads();
    const float sc = 65536.0f / s[t0 + tx];
    H2U cv; cv.h = (_Float16)(tile[tx][ty] * sc);
    xsT[(size_t)(b0 + ty) * TOPIC + t0 + tx] = cv.u;
}

// ---------------------------------------------------------------------------
// K3: out[v, b0..] = (E @ xsT^T) * 2^-16. 256x256 tile, same 4-phase schedule,
//     both operands gload_lds. Dispatch 1: col-chunks 1..3; dispatch 2: chunk 0
//     (those bytes ARE E -> runs last; own E reads drained before epilogue).
// ---------------------------------------------------------------------------
__global__ __launch_bounds__(512, 2) void gemm2_kernel(
    const u16* __restrict__ Eg, const u16* __restrict__ xsT,
    float* __restrict__ out, int c0, int nch)
{
    __shared__ char lds[131072];

    const int tid  = threadIdx.x;
    const int lane = tid & 63;
    const int wid  = tid >> 6;
    const int wr = wid >> 2, wc = wid & 3;
    const int lr = lane & 15, lk = lane >> 4;
    const int srow8  = lane >> 3;
    const int schunk = ((lane & 7) ^ srow8) * 8;

    const int bid   = xcd_swz(blockIdx.x, gridDim.x);
    const int tile  = bid / nch;
    const int chunk = bid % nch;
    const int v0 = tile * 256, b0 = (c0 + chunk) * 256;

    f32x4 acc[8][4] = {};
    f16x8 af[4], bf[4];

    auto stageA = [&](int kt, int h) {
        char* dsta = lds + (kt & 1) * 65536 + h * 16384;
        #pragma unroll
        for (int q = 0; q < 2; ++q) {
            const u16* s_ = Eg + (size_t)(v0 + h * 128 + wid * 16 + q * 8 + srow8) * 2048
                          + kt * 64 + schunk;
            GLDS(s_, dsta + (wid * 16 + q * 8) * ROWB);
        }
    };
    auto stageB = [&](int kt, int h) {
        char* dstb = lds + (kt & 1) * 65536 + 32768 + h * 16384;
        #pragma unroll
        for (int q = 0; q < 2; ++q) {
            const u16* s_ = xsT + (size_t)(b0 + h * 128 + wid * 16 + q * 8 + srow8) * TOPIC
                          + kt * 64 + schunk;
            GLDS(s_, dstb + (wid * 16 + q * 8) * ROWB);
        }
    };

    stageA(0, 0); stageA(0, 1); stageB(0, 0); stageB(0, 1);

    for (int t = 0; t < 8; ++t) {
        char* bufA = lds + (t & 1) * 65536;
        char* bufB = bufA + 32768;
        const bool st = (t + 1) < 8;

        WVM0();
        SBAR();
        RD_A(0, 0); RD_B(0);
        if (st) stageA(t + 1, 0);
        MFMA16(0);
        SBAR();
        RD_A(1, 0);
        if (st) stageA(t + 1, 1);
        MFMA16(1);
        SBAR();
        RD_A(0, 1); RD_B(1);
        if (st) stageB(t + 1, 0);
        MFMA16(0);
        SBAR();
        RD_A(1, 1);
        if (st) stageB(t + 1, 1);
        MFMA16(1);
    }

    #pragma unroll
    for (int mh = 0; mh < 2; ++mh)
      #pragma unroll
      for (int m = 0; m < 4; ++m)
        #pragma unroll
        for (int n = 0; n < 4; ++n)
          #pragma unroll
          for (int r = 0; r < 4; ++r) {
              const int row = wr * 128 + mh * 64 + m * 16 + lk * 4 + r;
              const int col = wc * 64 + n * 16 + lr;
              out[(size_t)(v0 + row) * BATCH + b0 + col] = acc[mh * 4 + m][n][r] * 0x1p-16f;
          }
}

// ---------------------------------------------------------------------------
extern "C" void kernel_launch(void* const* d_in, const int* in_sizes, int n_in,
                              void* d_out, int out_size, void* d_ws, size_t ws_size,
                              hipStream_t stream)
{
    const float* x     = (const float*)d_in[0];
    const float* beta0 = (const float*)d_in[1];
    const float* betat = (const float*)d_in[2];
    float* out = (float*)d_out;

    const size_t need_min = 4096 + (size_t)BATCH * TOPIC * 2;   // ~1.05 MB (proven)
    if (ws_size < need_min) return;
    float* s_g  = (float*)d_ws;
    u16*   buf1 = (u16*)((char*)d_ws + 4096);

    hipMemsetAsync(d_ws, 0, 2048, stream);                    // zero s accumulators
    cvt_betat_kernel<<<256, 256, 0, stream>>>(betat, buf1);   // buf1 = betat f16

    // E[v][t] lives in the first 1024 B of out row v (stride 4096 B)
    u16* EgO = (u16*)d_out;
    gemm1_kernel<<<1000, 512, 0, stream>>>(beta0, buf1, EgO, s_g);

    xst_kernel<<<dim3(BATCH / 32, TOPIC / 32), dim3(32, 32), 0, stream>>>(x, s_g, buf1);

    gemm2_kernel<<<1500, 512, 0, stream>>>(EgO, buf1, out, 1, 3);  // cols 256..1023
    gemm2_kernel<<<500,  512, 0, stream>>>(EgO, buf1, out, 0, 1);  // cols 0..255 (E bytes)
}

// Round 8
// 506.747 us; speedup vs baseline: 1.1238x; 1.1238x over previous
//
#include <hip/hip_runtime.h>

typedef _Float16 f16x8 __attribute__((ext_vector_type(8)));
typedef float    f32x4 __attribute__((ext_vector_type(4)));
typedef unsigned short u16;

#define VOC   128000
#define TOPIC 512
#define EMB   1024
#define BATCH 1024

// BK=32 layout: LDS row = 32 f16 = 64 B. XOR-swizzle spreads the 4 16B-chunks
// of a column-read across banks: byte ^= ((row>>1)&3)<<4. Applied identically
// on gload-source, ds_write, and ds_read (both-sides rule).
__device__ __forceinline__ int swz32(int row, int kbyte) {
    return row * 64 + (kbyte ^ (((row >> 1) & 3) << 4));
}
// Bijective XCD-chunked swizzle (m204), any nwg.
__device__ __forceinline__ int xcd_swz(int bid, int nwg) {
    int x = bid & 7, o = bid >> 3, q = nwg >> 3, r = nwg & 7;
    return (x < r ? x * (q + 1) : r * (q + 1) + (x - r) * q) + o;
}
union H2U { _Float16 h; u16 u; };

#define SBAR() asm volatile("s_barrier" ::: "memory")
#define WVM0() asm volatile("s_waitcnt vmcnt(0)" ::: "memory")
#define WVM4() asm volatile("s_waitcnt vmcnt(4)" ::: "memory")
#define WVM8() asm volatile("s_waitcnt vmcnt(8)" ::: "memory")
#define WLG0() asm volatile("s_waitcnt lgkmcnt(0)" ::: "memory")

#define GLDS(SRC, DST) __builtin_amdgcn_global_load_lds( \
    (const __attribute__((address_space(1))) unsigned int*)(SRC), \
    (__attribute__((address_space(3))) unsigned int*)(DST), 16, 0, 0)

// Per-buffer layout: A (256 rows x 64 B = 16 KB) @ +0, B @ +16384. 4 bufs x 32 KB.
#define RD_A(BUF, MH) { _Pragma("unroll") \
    for (int m = 0; m < 4; ++m) \
        af[m] = *(const f16x8*)((BUF) + swz32(wr * 128 + (MH) * 64 + m * 16 + lr, lk * 16)); }
#define RD_B(BUF) { _Pragma("unroll") \
    for (int n = 0; n < 4; ++n) \
        bf[n] = *(const f16x8*)((BUF) + 16384 + swz32(wc * 64 + n * 16 + lr, lk * 16)); }
#define MFMA16(MH) { \
    __builtin_amdgcn_s_setprio(1); \
    _Pragma("unroll") for (int m = 0; m < 4; ++m) \
    _Pragma("unroll") for (int n = 0; n < 4; ++n) \
        acc[(MH) * 4 + m][n] = __builtin_amdgcn_mfma_f32_16x16x32_f16( \
            af[m], bf[n], acc[(MH) * 4 + m][n], 0, 0, 0); \
    __builtin_amdgcn_s_setprio(0); }

// ---------------------------------------------------------------------------
// K0: betat f32 -> f16 (into the ws MB that xst later overwrites with xsT)
// ---------------------------------------------------------------------------
__global__ void cvt_betat_kernel(const float* __restrict__ betat, u16* __restrict__ bt16) {
    const size_t g = (size_t)blockIdx.x * 256 + threadIdx.x;
    const float4* src = reinterpret_cast<const float4*>(betat) + g * 2;
    float4 a = src[0], b = src[1];
    f16x8 h;
    h[0]=(_Float16)a.x; h[1]=(_Float16)a.y; h[2]=(_Float16)a.z; h[3]=(_Float16)a.w;
    h[4]=(_Float16)b.x; h[5]=(_Float16)b.y; h[6]=(_Float16)b.z; h[7]=(_Float16)b.w;
    *(reinterpret_cast<f16x8*>(bt16) + g) = h;
}

// ---------------------------------------------------------------------------
// K1: W = beta0 [V,E] @ bt16^T; E = f16(exp(W)) -> first 1024 B of out rows;
//     col sums. 256x256 tile, BK=32, 32 K-tiles, quad-buffer depth-3 pipeline,
//     counted vmcnt (steady-state no-op), 2 phases x 16 MFMA per tile.
// ---------------------------------------------------------------------------
__global__ __launch_bounds__(512, 2) void gemm1_kernel(
    const float* __restrict__ beta0, const u16* __restrict__ bt16,
    u16* __restrict__ Eg, float* __restrict__ sg)
{
    __shared__ char lds[131072];

    const int tid  = threadIdx.x;
    const int lane = tid & 63;
    const int wid  = tid >> 6;
    const int wr = wid >> 2, wc = wid & 3;
    const int lr = lane & 15, lk = lane >> 4;
    const int srcRow   = lane >> 2;
    const int srcChunk = (lane & 3) ^ ((lane >> 3) & 3);   // pre-swizzled source

    const int bid   = xcd_swz(blockIdx.x, gridDim.x);
    const int tile  = bid >> 1;
    const int chunk = bid & 1;
    const int v0 = tile * 256, t0 = chunk * 256;

    const int arow = tid >> 1, ahalf = tid & 1;   // A stage: 16 f32 per thread
    const float* aBase = beta0 + (size_t)(v0 + arow) * EMB + ahalf * 16;

    f32x4 acc[8][4] = {};
    f16x8 af[4], bf[4];
    float4 rEv[4], rOd[4];

#define G1_LOADA(R, KT) { const float4* gp = (const float4*)(aBase + (KT) * 32); \
    R[0] = gp[0]; R[1] = gp[1]; R[2] = gp[2]; R[3] = gp[3]; }
#define G1_CVT(R, KT1) { char* dA = lds + ((KT1) & 3) * 32768; \
    f16x8 h0, h1; \
    h0[0]=(_Float16)R[0].x; h0[1]=(_Float16)R[0].y; h0[2]=(_Float16)R[0].z; h0[3]=(_Float16)R[0].w; \
    h0[4]=(_Float16)R[1].x; h0[5]=(_Float16)R[1].y; h0[6]=(_Float16)R[1].z; h0[7]=(_Float16)R[1].w; \
    h1[0]=(_Float16)R[2].x; h1[1]=(_Float16)R[2].y; h1[2]=(_Float16)R[2].z; h1[3]=(_Float16)R[2].w; \
    h1[4]=(_Float16)R[3].x; h1[5]=(_Float16)R[3].y; h1[6]=(_Float16)R[3].z; h1[7]=(_Float16)R[3].w; \
    *(f16x8*)(dA + swz32(arow, (ahalf * 2) * 16)) = h0; \
    *(f16x8*)(dA + swz32(arow, (ahalf * 2 + 1) * 16)) = h1; }

    auto stageB_ = [&](int kt) {   // B(kt): 256 rows x 32 f16, 2 GLDS/wave
        char* dst = lds + (kt & 3) * 32768 + 16384;
        const u16* s0 = bt16 + (size_t)(t0 + wid * 32 + srcRow) * EMB + kt * 32 + srcChunk * 8;
        GLDS(s0, dst + wid * 32 * 64);
        GLDS(s0 + (size_t)16 * EMB, dst + (wid * 32 + 16) * 64);
    };

    // Prologue: B(0..2) in flight; A(0) cvt'd to LDS (its reg-wait drains B(0));
    // A(1) in rOd for tile 0.
    stageB_(0);
    G1_LOADA(rEv, 0);
    stageB_(1); stageB_(2);
    G1_LOADA(rOd, 1);
    G1_CVT(rEv, 0);
    WLG0();

    // Tile t: P0 {read A(mh0)+B, issue A(t+2) f32 loads, 16 MFMA}
    //         P1 {read A(mh1), cvt+write A(t+1), issue B(t+3) GLDS, 16 MFMA}
    // Top wait vmcnt(8): drains tile t only; t+1/t+2 stay in flight.
#define G1_TILE(T, RC, RI) { \
    WVM8(); SBAR(); \
    char* buf = lds + ((T) & 3) * 32768; \
    RD_A(buf, 0); RD_B(buf); \
    if ((T) + 2 < 32) G1_LOADA(RI, (T) + 2); \
    MFMA16(0); \
    SBAR(); \
    RD_A(buf, 1); \
    if ((T) + 1 < 32) G1_CVT(RC, (T) + 1); \
    if ((T) + 3 < 32) stageB_((T) + 3); \
    MFMA16(1); \
    WLG0(); }

    for (int tt = 0; tt < 16; ++tt) {
        const int t = tt * 2;
        G1_TILE(t,     rOd, rEv);
        G1_TILE(t + 1, rEv, rOd);
    }

    // Epilogue: 4 chunks of 64 rows; exp -> LDS repack -> E write + col sums
    __syncthreads();
    u16* ldsE = reinterpret_cast<u16*>(lds);   // 64 x 264 u16
    float csum = 0.f;
    #pragma unroll
    for (int c = 0; c < 4; ++c) {
        if (wr == (c >> 1)) {
            const int mb = (c & 1) * 4;
            #pragma unroll
            for (int m = 0; m < 4; ++m)
              #pragma unroll
              for (int n = 0; n < 4; ++n)
                #pragma unroll
                for (int r = 0; r < 4; ++r) {
                    const int row = m * 16 + lk * 4 + r;        // 0..63
                    const int col = wc * 64 + n * 16 + lr;      // 0..255
                    H2U cv; cv.h = (_Float16)__expf(acc[mb + m][n][r]);
                    ldsE[row * 264 + col] = cv.u;
                }
        }
        __syncthreads();
        {
            const int row8 = tid >> 3, seg = tid & 7;
            const int4* sp = reinterpret_cast<const int4*>(&ldsE[row8 * 264 + seg * 32]);
            u16* dst = Eg + (size_t)(v0 + c * 64 + row8) * 2048 + t0 + seg * 32;
            int4 a0 = sp[0], a1 = sp[1], a2 = sp[2], a3 = sp[3];
            int4* dp = reinterpret_cast<int4*>(dst);
            dp[0] = a0; dp[1] = a1; dp[2] = a2; dp[3] = a3;
        }
        if (tid < 256) {
            float s = 0.f;
            for (int r = 0; r < 64; ++r) { H2U cv; cv.u = ldsE[r * 264 + tid]; s += (float)cv.h; }
            csum += s;
        }
        __syncthreads();
    }
    if (tid < 256) atomicAdd(sg + t0 + tid, csum);
}

// ---------------------------------------------------------------------------
// K2: xsT[b][t] = f16( x[t][b] * 65536 / s[t] )
// ---------------------------------------------------------------------------
__global__ void xst_kernel(const float* __restrict__ x, const float* __restrict__ s,
                           u16* __restrict__ xsT)
{
    __shared__ float tile[32][33];
    const int b0 = blockIdx.x * 32, t0 = blockIdx.y * 32;
    const int tx = threadIdx.x, ty = threadIdx.y;
    tile[ty][tx] = x[(size_t)(t0 + ty) * BATCH + b0 + tx];
    __syncthreads();
    const float sc = 65536.0f / s[t0 + tx];
    H2U cv; cv.h = (_Float16)(tile[tx][ty] * sc);
    xsT[(size_t)(b0 + ty) * TOPIC + t0 + tx] = cv.u;
}

// ---------------------------------------------------------------------------
// K3: out[v, b0..] = (E @ xsT^T) * 2^-16. 256x256 tile, BK=32, 16 K-tiles,
//     quad-buffer depth-3, counted vmcnt(8)/(4)/(0), both operands gload_lds.
//     Dispatch 1: col-chunks 1..3; dispatch 2: chunk 0 (bytes ARE E, self-
//     contained per block: all E reads drained at t=15 top before out writes).
// ---------------------------------------------------------------------------
__global__ __launch_bounds__(512, 2) void gemm2_kernel(
    const u16* __restrict__ Eg, const u16* __restrict__ xsT,
    float* __restrict__ out, int c0, int nch)
{
    __shared__ char lds[131072];

    const int tid  = threadIdx.x;
    const int lane = tid & 63;
    const int wid  = tid >> 6;
    const int wr = wid >> 2, wc = wid & 3;
    const int lr = lane & 15, lk = lane >> 4;
    const int srcRow   = lane >> 2;
    const int srcChunk = (lane & 3) ^ ((lane >> 3) & 3);

    const int bid   = xcd_swz(blockIdx.x, gridDim.x);
    const int tile  = bid / nch;
    const int chunk = bid % nch;
    const int v0 = tile * 256, b0 = (c0 + chunk) * 256;

    f32x4 acc[8][4] = {};
    f16x8 af[4], bf[4];

    auto stageA_ = [&](int kt) {
        char* dst = lds + (kt & 3) * 32768;
        const u16* s0 = Eg + (size_t)(v0 + wid * 32 + srcRow) * 2048 + kt * 32 + srcChunk * 8;
        GLDS(s0, dst + wid * 32 * 64);
        GLDS(s0 + (size_t)16 * 2048, dst + (wid * 32 + 16) * 64);
    };
    auto stageB_ = [&](int kt) {
        char* dst = lds + (kt & 3) * 32768 + 16384;
        const u16* s0 = xsT + (size_t)(b0 + wid * 32 + srcRow) * TOPIC + kt * 32 + srcChunk * 8;
        GLDS(s0, dst + wid * 32 * 64);
        GLDS(s0 + (size_t)16 * TOPIC, dst + (wid * 32 + 16) * 64);
    };

    stageA_(0); stageB_(0); stageA_(1); stageB_(1); stageA_(2); stageB_(2);

    for (int t = 0; t < 16; ++t) {
        if (t <= 13) { WVM8(); } else if (t == 14) { WVM4(); } else { WVM0(); }
        SBAR();
        char* buf = lds + (t & 3) * 32768;
        RD_A(buf, 0); RD_B(buf);
        if (t + 3 < 16) stageA_(t + 3);
        MFMA16(0);
        SBAR();
        RD_A(buf, 1);
        if (t + 3 < 16) stageB_(t + 3);
        MFMA16(1);
    }

    #pragma unroll
    for (int mh = 0; mh < 2; ++mh)
      #pragma unroll
      for (int m = 0; m < 4; ++m)
        #pragma unroll
        for (int n = 0; n < 4; ++n)
          #pragma unroll
          for (int r = 0; r < 4; ++r) {
              const int row = wr * 128 + mh * 64 + m * 16 + lk * 4 + r;
              const int col = wc * 64 + n * 16 + lr;
              out[(size_t)(v0 + row) * BATCH + b0 + col] = acc[mh * 4 + m][n][r] * 0x1p-16f;
          }
}

// ---------------------------------------------------------------------------
extern "C" void kernel_launch(void* const* d_in, const int* in_sizes, int n_in,
                              void* d_out, int out_size, void* d_ws, size_t ws_size,
                              hipStream_t stream)
{
    const float* x     = (const float*)d_in[0];
    const float* beta0 = (const float*)d_in[1];
    const float* betat = (const float*)d_in[2];
    float* out = (float*)d_out;

    const size_t need_min = 4096 + (size_t)BATCH * TOPIC * 2;   // ~1.05 MB (proven)
    if (ws_size < need_min) return;
    float* s_g  = (float*)d_ws;
    u16*   buf1 = (u16*)((char*)d_ws + 4096);

    hipMemsetAsync(d_ws, 0, 2048, stream);                    // zero s accumulators
    cvt_betat_kernel<<<256, 256, 0, stream>>>(betat, buf1);   // buf1 = betat f16

    // E[v][t] lives in the first 1024 B of out row v (stride 4096 B)
    u16* EgO = (u16*)d_out;
    gemm1_kernel<<<1000, 512, 0, stream>>>(beta0, buf1, EgO, s_g);

    xst_kernel<<<dim3(BATCH / 32, TOPIC / 32), dim3(32, 32), 0, stream>>>(x, s_g, buf1);

    gemm2_kernel<<<1500, 512, 0, stream>>>(EgO, buf1, out, 1, 3);  // cols 256..1023
    gemm2_kernel<<<500,  512, 0, stream>>>(EgO, buf1, out, 0, 1);  // cols 0..255 (E bytes)
}